// Round 2
// baseline (503.475 us; speedup 1.0000x reference)
//
#include <hip/hip_runtime.h>

typedef unsigned short u16;
typedef unsigned int u32;

using bf16x8 = __attribute__((ext_vector_type(8))) __bf16;
using f32x4  = __attribute__((ext_vector_type(4))) float;
using u16x8  = __attribute__((ext_vector_type(8))) u16;

#define BB 4
#define TT 4096
#define DD 2048
#define MM 16384
#define KK 2048
#define NCHUNK 16
#define CLEN 256

__device__ __forceinline__ u16 f2bf(float f) {
    u32 u = __float_as_uint(f);
    u32 r = (u + 0x7FFFu + ((u >> 16) & 1u)) >> 16;
    return (u16)r;
}

__device__ __forceinline__ void gload_lds16(const void* g, void* l) {
    __builtin_amdgcn_global_load_lds(
        (const __attribute__((address_space(1))) void*)g,
        (__attribute__((address_space(3))) void*)l, 16, 0, 0);
}

#define BAR() do { __builtin_amdgcn_sched_barrier(0); __builtin_amdgcn_s_barrier(); __builtin_amdgcn_sched_barrier(0); } while(0)
#define WAIT_LGKM0() do { asm volatile("s_waitcnt lgkmcnt(0)" ::: "memory"); __builtin_amdgcn_sched_barrier(0); } while(0)
#define WAIT_VM8() do { asm volatile("s_waitcnt vmcnt(8)" ::: "memory"); __builtin_amdgcn_sched_barrier(0); } while(0)
#define WAIT_VM4() do { asm volatile("s_waitcnt vmcnt(4)" ::: "memory"); __builtin_amdgcn_sched_barrier(0); } while(0)
#define WAIT_VM0() do { asm volatile("s_waitcnt vmcnt(0)" ::: "memory"); __builtin_amdgcn_sched_barrier(0); } while(0)

// ---------------- fp32 -> bf16 convert (8 elems/thread) ----------------
__global__ __launch_bounds__(256) void cvt_kernel(const float* __restrict__ in,
                                                  u16* __restrict__ out, int n8) {
    int i = blockIdx.x * 256 + threadIdx.x;
    if (i >= n8) return;
    const f32x4* p = (const f32x4*)in + (size_t)i * 2;
    f32x4 a = p[0], b = p[1];
    u16x8 o;
    o[0] = f2bf(a[0]); o[1] = f2bf(a[1]); o[2] = f2bf(a[2]); o[3] = f2bf(a[3]);
    o[4] = f2bf(b[0]); o[5] = f2bf(b[1]); o[6] = f2bf(b[2]); o[7] = f2bf(b[3]);
    *((u16x8*)out + i) = o;
}

// ---------------- fused dual GEMM (8-phase pipeline) + gate epilogue ----------------
// Tile: 256(M) x 128(e), BK=32, 4-deep LDS pipeline, 8 waves (2M x 4N).
// g  = 8*softplus(lam[e])*sigmoid(gate_rec+b_gate)
// xb = sqrt(1-exp(-2g)+1e-6)*sigmoid(gate_in+b_in)*x[m,e]
// pair[m,e] = bf16(g) | bf16(xb)<<16
#define BMg 256
#define BNg 128
#define BKg 32
#define NT (KK / BKg)   // 64 K-steps

__global__ __launch_bounds__(512, 2) void gemm_dual8(
    const u16* __restrict__ xb, const u16* __restrict__ wib, const u16* __restrict__ wgb,
    const float* __restrict__ xf,
    const float* __restrict__ b_in, const float* __restrict__ b_gate,
    const float* __restrict__ lam, u32* __restrict__ pair)
{
    __shared__ u16 As[4][BMg * BKg];       // 4 x 16 KB
    __shared__ u16 Bs[4][2][BNg * BKg];    // 4 x 2 x 8 KB   (total 128 KB)

    const int tid = threadIdx.x;
    const int bid = blockIdx.x;
    const int cpx = gridDim.x >> 3;               // 1024 % 8 == 0 -> bijective
    const int swz = (bid & 7) * cpx + (bid >> 3);
    const int et = swz & 15;
    const int mt = swz >> 4;
    const size_t m0 = (size_t)mt * BMg;
    const size_t e0 = (size_t)et * BNg;

    const int lane = tid & 63;
    const int wid = tid >> 6;
    const int wr = wid >> 2;    // 0..1 -> m offset wr*128
    const int wc = wid & 3;     // 0..3 -> e offset wc*32
    const int r15 = lane & 15;
    const int s4 = lane >> 4;   // 0..3 k-segment

    // --- staging map (T2 swizzle on the GLOBAL side; LDS dest stays linear) ---
    const int srow = tid >> 2;                       // 0..127
    const int sseg = (tid & 3) ^ ((tid >> 3) & 3);   // swizzled 16B segment
    const int skp  = sseg << 3;                      // element offset in k

    // --- read-side swizzled k offset (involution of the staging swizzle) ---
    const int koff = ((s4 ^ ((r15 >> 1) & 3)) << 3);

#define STAGE_A(t) do { int _b = (t) & 3; size_t _k = (size_t)(t) * BKg + skp; \
        gload_lds16(xb + (m0 + srow) * KK + _k,        &As[_b][tid * 8]); \
        gload_lds16(xb + (m0 + 128 + srow) * KK + _k,  &As[_b][4096 + tid * 8]); } while (0)
#define STAGE_B(t) do { int _b = (t) & 3; size_t _k = (size_t)(t) * BKg + skp; \
        gload_lds16(wib + (e0 + srow) * KK + _k, &Bs[_b][0][tid * 8]); \
        gload_lds16(wgb + (e0 + srow) * KK + _k, &Bs[_b][1][tid * 8]); } while (0)

    f32x4 accI[8][2], accG[8][2];
#pragma unroll
    for (int i = 0; i < 8; i++)
#pragma unroll
        for (int j = 0; j < 2; j++) {
            accI[i][j] = (f32x4){0.f, 0.f, 0.f, 0.f};
            accG[i][j] = (f32x4){0.f, 0.f, 0.f, 0.f};
        }

    // prologue: stage K-steps 0,1,2
    STAGE_A(0); STAGE_B(0);
    STAGE_A(1); STAGE_B(1);
    STAGE_A(2); STAGE_B(2);
    WAIT_VM8();   // drain step-0's 4 loads (8 remain for steps 1,2)
    BAR();

    for (int t = 0; t < NT; ++t) {
        const int cb = t & 3;
        const u16* Ab = &As[cb][0];
        const u16* BiB = &Bs[cb][0][0];
        const u16* BgB = &Bs[cb][1][0];
        bf16x8 bI[2], bG[2], aF[4];

        // ---- phase 0: mi 0..3 ----
#pragma unroll
        for (int q = 0; q < 4; q++)
            aF[q] = *(const bf16x8*)&Ab[(wr * 128 + q * 16 + r15) * BKg + koff];
#pragma unroll
        for (int ni = 0; ni < 2; ni++) {
            bI[ni] = *(const bf16x8*)&BiB[(wc * 32 + ni * 16 + r15) * BKg + koff];
            bG[ni] = *(const bf16x8*)&BgB[(wc * 32 + ni * 16 + r15) * BKg + koff];
        }
        if (t < NT - 3) STAGE_A(t + 3);
        BAR();
        WAIT_LGKM0();
        __builtin_amdgcn_s_setprio(1);
#pragma unroll
        for (int q = 0; q < 4; q++)
#pragma unroll
            for (int ni = 0; ni < 2; ni++) {
                accI[q][ni] = __builtin_amdgcn_mfma_f32_16x16x32_bf16(aF[q], bI[ni], accI[q][ni], 0, 0, 0);
                accG[q][ni] = __builtin_amdgcn_mfma_f32_16x16x32_bf16(aF[q], bG[ni], accG[q][ni], 0, 0, 0);
            }
        __builtin_amdgcn_s_setprio(0);
        BAR();

        // ---- phase 1: mi 4..7 ----
#pragma unroll
        for (int q = 0; q < 4; q++)
            aF[q] = *(const bf16x8*)&Ab[(wr * 128 + (q + 4) * 16 + r15) * BKg + koff];
        if (t < NT - 3) STAGE_B(t + 3);
        BAR();
        WAIT_LGKM0();
        __builtin_amdgcn_s_setprio(1);
#pragma unroll
        for (int q = 0; q < 4; q++)
#pragma unroll
            for (int ni = 0; ni < 2; ni++) {
                accI[q + 4][ni] = __builtin_amdgcn_mfma_f32_16x16x32_bf16(aF[q], bI[ni], accI[q + 4][ni], 0, 0, 0);
                accG[q + 4][ni] = __builtin_amdgcn_mfma_f32_16x16x32_bf16(aF[q], bG[ni], accG[q + 4][ni], 0, 0, 0);
            }
        __builtin_amdgcn_s_setprio(0);
        // counted vmcnt: drain (t+1)'s 4 loads; keep t+2,t+3 in flight
        if (t < NT - 3)      WAIT_VM8();
        else if (t == NT - 3) WAIT_VM4();
        else                  WAIT_VM0();
        BAR();
    }

    // ---- epilogue ----
    float spl[2], biv[2], bgv[2];
    size_t ecol[2];
#pragma unroll
    for (int ni = 0; ni < 2; ni++) {
        size_t e = e0 + wc * 32 + ni * 16 + r15;
        ecol[ni] = e;
        spl[ni] = 8.0f * log1pf(__expf(lam[e]));
        biv[ni] = b_in[e];
        bgv[ni] = b_gate[e];
    }
    const int rbase = s4 * 4;
#pragma unroll
    for (int mi = 0; mi < 8; mi++) {
#pragma unroll
        for (int r = 0; r < 4; r++) {
            size_t m = m0 + wr * 128 + mi * 16 + rbase + r;
#pragma unroll
            for (int ni = 0; ni < 2; ni++) {
                size_t e = ecol[ni];
                float ig = accI[mi][ni][r] + biv[ni];
                float rg = accG[mi][ni][r] + bgv[ni];
                float sigr = 1.f / (1.f + __expf(-rg));
                float g = spl[ni] * sigr;
                float beta = sqrtf(1.f - __expf(-2.f * g) + 1e-6f);
                float xv = xf[m * DD + e];
                float xbeta = beta * (1.f / (1.f + __expf(-ig))) * xv;
                u32 pk = (u32)f2bf(g) | (((u32)f2bf(xbeta)) << 16);
                pair[m * DD + e] = pk;
            }
        }
    }
#undef STAGE_A
#undef STAGE_B
}

// ---------------- chunked scan ----------------
// pair layout [B,T,D]: low16 = bf16(g), high16 = bf16(xbeta); alpha = exp(-g)
__global__ __launch_bounds__(256) void scanA(const u32* __restrict__ pair,
                                             float* __restrict__ aggG,
                                             float* __restrict__ aggB) {
    int gid = blockIdx.x * 256 + threadIdx.x;   // 131072
    int e = gid & (DD - 1);
    int rest = gid >> 11;     // 0..63
    int b = rest & 3;
    int c = rest >> 2;        // 0..15
    const u32* p = pair + ((size_t)(b * TT + c * CLEN)) * DD + e;
    float gsum = 0.f, h = 0.f;
#pragma unroll 4
    for (int t = 0; t < CLEN; ++t) {
        u32 v = *p; p += DD;
        float gf = __uint_as_float(v << 16);
        float xbv = __uint_as_float(v & 0xFFFF0000u);
        gsum += gf;
        h = fmaf(__expf(-gf), h, xbv);
    }
    int idx = ((b * NCHUNK + c) << 11) | e;
    aggG[idx] = gsum;
    aggB[idx] = h;
}

__global__ __launch_bounds__(256) void scanB(const float* __restrict__ aggG,
                                             const float* __restrict__ aggB,
                                             float* __restrict__ carry) {
    int gid = blockIdx.x * 256 + threadIdx.x;   // 8192
    int e = gid & (DD - 1);
    int b = gid >> 11;
    float h = 0.f;
#pragma unroll
    for (int c = 0; c < NCHUNK; ++c) {
        int idx = ((b * NCHUNK + c) << 11) | e;
        carry[idx] = h;
        h = fmaf(__expf(-aggG[idx]), h, aggB[idx]);
    }
}

__global__ __launch_bounds__(256) void scanC(const u32* __restrict__ pair,
                                             const float* __restrict__ carry,
                                             float* __restrict__ out) {
    int gid = blockIdx.x * 256 + threadIdx.x;   // 131072
    int e = gid & (DD - 1);
    int rest = gid >> 11;
    int b = rest & 3;
    int c = rest >> 2;
    const u32* p = pair + ((size_t)(b * TT + c * CLEN)) * DD + e;
    float* o = out + ((size_t)(b * TT + c * CLEN)) * DD + e;
    float h = carry[((b * NCHUNK + c) << 11) | e];
#pragma unroll 4
    for (int t = 0; t < CLEN; ++t) {
        u32 v = *p; p += DD;
        float gf = __uint_as_float(v << 16);
        float xbv = __uint_as_float(v & 0xFFFF0000u);
        h = fmaf(__expf(-gf), h, xbv);
        *o = h; o += DD;
    }
}

extern "C" void kernel_launch(void* const* d_in, const int* in_sizes, int n_in,
                              void* d_out, int out_size, void* d_ws, size_t ws_size,
                              hipStream_t stream) {
    const float* x      = (const float*)d_in[0];
    const float* W_in   = (const float*)d_in[1];
    const float* b_in   = (const float*)d_in[2];
    const float* W_gate = (const float*)d_in[3];
    const float* b_gate = (const float*)d_in[4];
    const float* lam    = (const float*)d_in[5];
    float* out = (float*)d_out;

    char* ws = (char*)d_ws;
    u16* xb   = (u16*)(ws);                  // 67,108,864 B
    u16* wib  = (u16*)(ws + 67108864);       //  8,388,608 B
    u16* wgb  = (u16*)(ws + 75497472);       //  8,388,608 B
    u32* pair = (u32*)(ws + 83886080);       // 134,217,728 B
    float* aggG  = (float*)(ws + 218103808); // 524,288 B
    float* aggB  = (float*)(ws + 218628096); // 524,288 B
    float* carry = (float*)(ws + 219152384); // 524,288 B

    cvt_kernel<<<16384, 256, 0, stream>>>(x, xb, MM * KK / 8);
    cvt_kernel<<<2048, 256, 0, stream>>>(W_in, wib, DD * KK / 8);
    cvt_kernel<<<2048, 256, 0, stream>>>(W_gate, wgb, DD * KK / 8);
    gemm_dual8<<<(MM / BMg) * (DD / BNg), 512, 0, stream>>>(xb, wib, wgb, x, b_in, b_gate, lam, pair);
    scanA<<<BB * DD * NCHUNK / 256, 256, 0, stream>>>(pair, aggG, aggB);
    scanB<<<BB * DD / 256, 256, 0, stream>>>(aggG, aggB, carry);
    scanC<<<BB * DD * NCHUNK / 256, 256, 0, stream>>>(pair, carry, out);
}

// Round 3
// 436.326 us; speedup vs baseline: 1.1539x; 1.1539x over previous
//
#include <hip/hip_runtime.h>

typedef unsigned short u16;
typedef unsigned int u32;

using bf16x8 = __attribute__((ext_vector_type(8))) __bf16;
using f32x4  = __attribute__((ext_vector_type(4))) float;
using u16x8  = __attribute__((ext_vector_type(8))) u16;

#define BB 4
#define TT 4096
#define DD 2048
#define MM 16384
#define KK 2048
#define NCHUNK 16
#define CLEN 256

__device__ __forceinline__ u16 f2bf(float f) {
    u32 u = __float_as_uint(f);
    u32 r = (u + 0x7FFFu + ((u >> 16) & 1u)) >> 16;
    return (u16)r;
}

__device__ __forceinline__ void gload_lds16(const void* g, void* l) {
    __builtin_amdgcn_global_load_lds(
        (const __attribute__((address_space(1))) void*)g,
        (__attribute__((address_space(3))) void*)l, 16, 0, 0);
}

// ---------------- fp32 -> bf16 convert (8 elems/thread) ----------------
__global__ __launch_bounds__(256) void cvt_kernel(const float* __restrict__ in,
                                                  u16* __restrict__ out, int n8) {
    int i = blockIdx.x * 256 + threadIdx.x;
    if (i >= n8) return;
    const f32x4* p = (const f32x4*)in + (size_t)i * 2;
    f32x4 a = p[0], b = p[1];
    u16x8 o;
    o[0] = f2bf(a[0]); o[1] = f2bf(a[1]); o[2] = f2bf(a[2]); o[3] = f2bf(a[3]);
    o[4] = f2bf(b[0]); o[5] = f2bf(b[1]); o[6] = f2bf(b[2]); o[7] = f2bf(b[3]);
    *((u16x8*)out + i) = o;
}

// ---------------- fused dual GEMM (8-phase pipeline) + gate epilogue ----------------
// Tile: 256(M) x 128(e), BK=32, 4-deep LDS pipeline, 8 waves (2M x 4N).
// Only ONE scheduling pin per phase (rule 18); everything else free.
#define BMg 256
#define BNg 128
#define BKg 32
#define NT (KK / BKg)   // 64 K-steps

__global__ __launch_bounds__(512, 2) void gemm_dual8(
    const u16* __restrict__ xb, const u16* __restrict__ wib, const u16* __restrict__ wgb,
    const float* __restrict__ b_in, const float* __restrict__ b_gate,
    const float* __restrict__ lam, u32* __restrict__ pair)
{
    __shared__ u16 As[4][BMg * BKg];       // 4 x 16 KB
    __shared__ u16 Bs[4][2][BNg * BKg];    // 4 x 2 x 8 KB   (total 128 KB)

    const int tid = threadIdx.x;
    const int bid = blockIdx.x;
    const int cpx = gridDim.x >> 3;               // 1024 % 8 == 0 -> bijective
    const int swz = (bid & 7) * cpx + (bid >> 3);
    const int et = swz & 15;
    const int mt = swz >> 4;
    const size_t m0 = (size_t)mt * BMg;
    const size_t e0 = (size_t)et * BNg;

    const int lane = tid & 63;
    const int wid = tid >> 6;
    const int wr = wid >> 2;    // 0..1 -> m offset wr*128
    const int wc = wid & 3;     // 0..3 -> e offset wc*32
    const int r15 = lane & 15;
    const int s4 = lane >> 4;   // 0..3 k-segment

    // staging map (T2 swizzle on the GLOBAL side; LDS dest stays linear)
    const int srow = tid >> 2;                       // 0..127
    const int sseg = (tid & 3) ^ ((tid >> 3) & 3);   // swizzled 16B segment
    const int skp  = sseg << 3;

    // read-side swizzled k offset (involution of the staging swizzle)
    const int koff = ((s4 ^ ((r15 >> 1) & 3)) << 3);

    // precomputed global stage pointers (advance via t*BKg)
    const u16* gA0 = xb  + (m0 + srow) * KK + skp;
    const u16* gA1 = gA0 + (size_t)128 * KK;
    const u16* gI  = wib + (e0 + srow) * KK + skp;
    const u16* gG  = wgb + (e0 + srow) * KK + skp;

    // precomputed LDS read element-offsets (loop-invariant)
    int aoff[8], boff[2];
#pragma unroll
    for (int q = 0; q < 8; q++) aoff[q] = (wr * 128 + q * 16 + r15) * BKg + koff;
#pragma unroll
    for (int ni = 0; ni < 2; ni++) boff[ni] = (wc * 32 + ni * 16 + r15) * BKg + koff;

#define STAGE_A(t) do { int _b = (t) & 3; size_t _k = (size_t)(t) * BKg; \
        gload_lds16(gA0 + _k, &As[_b][tid * 8]); \
        gload_lds16(gA1 + _k, &As[_b][4096 + tid * 8]); } while (0)
#define STAGE_B(t) do { int _b = (t) & 3; size_t _k = (size_t)(t) * BKg; \
        gload_lds16(gI + _k, &Bs[_b][0][tid * 8]); \
        gload_lds16(gG + _k, &Bs[_b][1][tid * 8]); } while (0)

    f32x4 accI[8][2], accG[8][2];
#pragma unroll
    for (int i = 0; i < 8; i++)
#pragma unroll
        for (int j = 0; j < 2; j++) {
            accI[i][j] = (f32x4){0.f, 0.f, 0.f, 0.f};
            accG[i][j] = (f32x4){0.f, 0.f, 0.f, 0.f};
        }

    // prologue: stage K-steps 0,1,2
    STAGE_A(0); STAGE_B(0);
    STAGE_A(1); STAGE_B(1);
    STAGE_A(2); STAGE_B(2);
    asm volatile("s_waitcnt vmcnt(8)" ::: "memory");   // tile 0 resident
    __builtin_amdgcn_s_barrier();

#define PHASE0(t) do { \
        const u16* Ab = &As[(t) & 3][0]; \
        const u16* BiB = &Bs[(t) & 3][0][0]; \
        const u16* BgB = &Bs[(t) & 3][1][0]; \
        _Pragma("unroll") for (int q = 0; q < 4; q++) aF[q] = *(const bf16x8*)&Ab[aoff[q]]; \
        _Pragma("unroll") for (int ni = 0; ni < 2; ni++) { \
            bI[ni] = *(const bf16x8*)&BiB[boff[ni]]; \
            bG[ni] = *(const bf16x8*)&BgB[boff[ni]]; } \
    } while (0)
#define PHASE1(t) do { \
        const u16* Ab = &As[(t) & 3][0]; \
        _Pragma("unroll") for (int q = 0; q < 4; q++) aF[q] = *(const bf16x8*)&Ab[aoff[q + 4]]; \
    } while (0)
#define MFMA_BURST(base) do { \
        asm volatile("s_waitcnt lgkmcnt(0)" ::: "memory"); \
        __builtin_amdgcn_sched_barrier(0); \
        __builtin_amdgcn_s_setprio(1); \
        _Pragma("unroll") for (int q = 0; q < 4; q++) \
        _Pragma("unroll") for (int ni = 0; ni < 2; ni++) { \
            accI[q + (base)][ni] = __builtin_amdgcn_mfma_f32_16x16x32_bf16(aF[q], bI[ni], accI[q + (base)][ni], 0, 0, 0); \
            accG[q + (base)][ni] = __builtin_amdgcn_mfma_f32_16x16x32_bf16(aF[q], bG[ni], accG[q + (base)][ni], 0, 0, 0); } \
        __builtin_amdgcn_s_setprio(0); \
    } while (0)

    bf16x8 bI[2], bG[2], aF[4];

#pragma unroll 4
    for (int t = 0; t < NT - 3; ++t) {
        PHASE0(t);
        STAGE_A(t + 3);
        __builtin_amdgcn_s_barrier();
        MFMA_BURST(0);
        __builtin_amdgcn_s_barrier();
        PHASE1(t);
        STAGE_B(t + 3);
        __builtin_amdgcn_s_barrier();
        MFMA_BURST(4);
        asm volatile("s_waitcnt vmcnt(8)" ::: "memory");   // (t+1)'s 4 loads done
        __builtin_amdgcn_s_barrier();
    }
    // tail: t = NT-3, NT-2, NT-1 (no staging)
#pragma unroll 1
    for (int t = NT - 3; t < NT; ++t) {
        PHASE0(t);
        __builtin_amdgcn_s_barrier();
        MFMA_BURST(0);
        __builtin_amdgcn_s_barrier();
        PHASE1(t);
        __builtin_amdgcn_s_barrier();
        MFMA_BURST(4);
        if (t == NT - 3) asm volatile("s_waitcnt vmcnt(4)" ::: "memory");
        else             asm volatile("s_waitcnt vmcnt(0)" ::: "memory");
        __builtin_amdgcn_s_barrier();
    }

    // ---- epilogue ----
    float spl[2], biv[2], bgv[2];
    size_t ecol[2];
#pragma unroll
    for (int ni = 0; ni < 2; ni++) {
        size_t e = e0 + wc * 32 + ni * 16 + r15;
        ecol[ni] = e;
        spl[ni] = 8.0f * log1pf(__expf(lam[e]));
        biv[ni] = b_in[e];
        bgv[ni] = b_gate[e];
    }
    const int rbase = s4 * 4;
#pragma unroll
    for (int mi = 0; mi < 8; mi++) {
#pragma unroll
        for (int r = 0; r < 4; r++) {
            size_t m = m0 + wr * 128 + mi * 16 + rbase + r;
#pragma unroll
            for (int ni = 0; ni < 2; ni++) {
                size_t e = ecol[ni];
                float ig = accI[mi][ni][r] + biv[ni];
                float rg = accG[mi][ni][r] + bgv[ni];
                float sigr = 1.f / (1.f + __expf(-rg));
                float g = spl[ni] * sigr;
                float beta = sqrtf(1.f - __expf(-2.f * g) + 1e-6f);
                float xv = __uint_as_float((u32)xb[m * KK + e] << 16);  // L2-hot bf16 x
                float xbeta = beta * (1.f / (1.f + __expf(-ig))) * xv;
                u32 pk = (u32)f2bf(g) | (((u32)f2bf(xbeta)) << 16);
                pair[m * DD + e] = pk;
            }
        }
    }
#undef STAGE_A
#undef STAGE_B
#undef PHASE0
#undef PHASE1
#undef MFMA_BURST
}

// ---------------- chunked scan ----------------
// pair layout [B,T,D]: low16 = bf16(g), high16 = bf16(xbeta); alpha = exp(-g)
__global__ __launch_bounds__(256) void scanA(const u32* __restrict__ pair,
                                             float* __restrict__ aggG,
                                             float* __restrict__ aggB) {
    int gid = blockIdx.x * 256 + threadIdx.x;   // 131072
    int e = gid & (DD - 1);
    int rest = gid >> 11;     // 0..63
    int b = rest & 3;
    int c = rest >> 2;        // 0..15
    const u32* p = pair + ((size_t)(b * TT + c * CLEN)) * DD + e;
    float gsum = 0.f, h = 0.f;
#pragma unroll 4
    for (int t = 0; t < CLEN; ++t) {
        u32 v = *p; p += DD;
        float gf = __uint_as_float(v << 16);
        float xbv = __uint_as_float(v & 0xFFFF0000u);
        gsum += gf;
        h = fmaf(__expf(-gf), h, xbv);
    }
    int idx = ((b * NCHUNK + c) << 11) | e;
    aggG[idx] = gsum;
    aggB[idx] = h;
}

__global__ __launch_bounds__(256) void scanB(const float* __restrict__ aggG,
                                             const float* __restrict__ aggB,
                                             float* __restrict__ carry) {
    int gid = blockIdx.x * 256 + threadIdx.x;   // 8192
    int e = gid & (DD - 1);
    int b = gid >> 11;
    float h = 0.f;
#pragma unroll
    for (int c = 0; c < NCHUNK; ++c) {
        int idx = ((b * NCHUNK + c) << 11) | e;
        carry[idx] = h;
        h = fmaf(__expf(-aggG[idx]), h, aggB[idx]);
    }
}

__global__ __launch_bounds__(256) void scanC(const u32* __restrict__ pair,
                                             const float* __restrict__ carry,
                                             float* __restrict__ out) {
    int gid = blockIdx.x * 256 + threadIdx.x;   // 131072
    int e = gid & (DD - 1);
    int rest = gid >> 11;
    int b = rest & 3;
    int c = rest >> 2;
    const u32* p = pair + ((size_t)(b * TT + c * CLEN)) * DD + e;
    float* o = out + ((size_t)(b * TT + c * CLEN)) * DD + e;
    float h = carry[((b * NCHUNK + c) << 11) | e];
#pragma unroll 4
    for (int t = 0; t < CLEN; ++t) {
        u32 v = *p; p += DD;
        float gf = __uint_as_float(v << 16);
        float xbv = __uint_as_float(v & 0xFFFF0000u);
        h = fmaf(__expf(-gf), h, xbv);
        *o = h; o += DD;
    }
}

extern "C" void kernel_launch(void* const* d_in, const int* in_sizes, int n_in,
                              void* d_out, int out_size, void* d_ws, size_t ws_size,
                              hipStream_t stream) {
    const float* x      = (const float*)d_in[0];
    const float* W_in   = (const float*)d_in[1];
    const float* b_in   = (const float*)d_in[2];
    const float* W_gate = (const float*)d_in[3];
    const float* b_gate = (const float*)d_in[4];
    const float* lam    = (const float*)d_in[5];
    float* out = (float*)d_out;

    char* ws = (char*)d_ws;
    u16* xb   = (u16*)(ws);                  // 67,108,864 B
    u16* wib  = (u16*)(ws + 67108864);       //  8,388,608 B
    u16* wgb  = (u16*)(ws + 75497472);       //  8,388,608 B
    u32* pair = (u32*)(ws + 83886080);       // 134,217,728 B
    float* aggG  = (float*)(ws + 218103808); // 524,288 B
    float* aggB  = (float*)(ws + 218628096); // 524,288 B
    float* carry = (float*)(ws + 219152384); // 524,288 B

    cvt_kernel<<<16384, 256, 0, stream>>>(x, xb, MM * KK / 8);
    cvt_kernel<<<2048, 256, 0, stream>>>(W_in, wib, DD * KK / 8);
    cvt_kernel<<<2048, 256, 0, stream>>>(W_gate, wgb, DD * KK / 8);
    gemm_dual8<<<(MM / BMg) * (DD / BNg), 512, 0, stream>>>(xb, wib, wgb, b_in, b_gate, lam, pair);
    scanA<<<BB * DD * NCHUNK / 256, 256, 0, stream>>>(pair, aggG, aggB);
    scanB<<<BB * DD / 256, 256, 0, stream>>>(aggG, aggB, carry);
    scanC<<<BB * DD * NCHUNK / 256, 256, 0, stream>>>(pair, carry, out);
}